// Round 2
// baseline (207.299 us; speedup 1.0000x reference)
//
#include <hip/hip_runtime.h>
#include <stdint.h>

typedef __attribute__((ext_vector_type(8)))  short  short8;
typedef __attribute__((ext_vector_type(8)))  __bf16 bf16x8;
typedef __attribute__((ext_vector_type(16))) float  floatx16;
typedef __attribute__((ext_vector_type(4)))  float  floatx4;

union Frag { short8 s; bf16x8 v; };

// round-to-nearest-even f32 -> bf16 (inputs are finite, no NaN handling needed)
__device__ __forceinline__ short f2bf(float f) {
    union { float f; uint32_t u; } x; x.f = f;
    uint32_t r = x.u + 0x7fffu + ((x.u >> 16) & 1u);
    return (short)(r >> 16);
}

__device__ __forceinline__ float fast_exp2(float x) {
#if __has_builtin(__builtin_amdgcn_exp2f)
    return __builtin_amdgcn_exp2f(x);
#else
    return exp2f(x);
#endif
}

__device__ __forceinline__ float fast_rcp(float x) {
#if __has_builtin(__builtin_amdgcn_rcpf)
    return __builtin_amdgcn_rcpf(x);
#else
    return 1.0f / x;
#endif
}

// y[b] = a0 + sum_k bk[k] * tanh(ck[k,:].z[b,:] + dk[k])
//
// D = mfma_32x32x16_bf16(A=s*ck, B=z, C=s*dk) -> D[node][row] = s*(dot+dk),
// s = 2*log2(e); col(lane&31)=batch row, row(reg-map)=node.
// tanh(t) = 1 - 2/(exp2(s*t)+1) -> contribution = bk - 2*bk*rcp(E+1).
// 32 in-lane node terms per batch row; one shfl_xor(32) merges the
// complementary half; coalesced dword stores from lanes 0..31.
//
// 2-deep software pipeline: issue next tile's two dwordx4 z-loads before
// the convert/MFMA/exp work of the current tile, so the ~900cy HBM latency
// hides behind ~700cy of in-wave compute (occupancy alone is only
// ~3-4 waves/SIMD at this VGPR count).
__global__ __launch_bounds__(256) void mave_kernel(
    const float* __restrict__ z,
    const float* __restrict__ a0,
    const float* __restrict__ bk,
    const float* __restrict__ ck,
    const float* __restrict__ dk,
    float* __restrict__ out,
    int ntiles)
{
    const int lane = threadIdx.x & 63;
    const int m    = lane & 31;   // node for A-frag; batch-row-in-tile for B-frag
    const int g    = lane >> 5;
    const float S  = 2.885390081777927f;  // 2*log2(e)

    // A-operand fragments: rows of s*ck (node = m and m+32), k = g*8+e
    Frag af0, af1;
    {
        const float* c0 = ck + m * 16 + g * 8;
        const float* c1 = c0 + 32 * 16;
        #pragma unroll
        for (int e = 0; e < 8; ++e) {
            af0.s[e] = f2bf(c0[e] * S);
            af1.s[e] = f2bf(c1[e] * S);
        }
    }

    // C-operand init = s*dk[node]; per-lane node map (reg&3)+8*(reg>>2)+4*g
    floatx16 cinit0, cinit1;
    float nb0[16], nb1[16];
    #pragma unroll
    for (int r = 0; r < 16; ++r) {
        int n = (r & 3) + 8 * (r >> 2) + 4 * g;
        cinit0[r] = S * dk[n];
        cinit1[r] = S * dk[n + 32];
        nb0[r] = -2.0f * bk[n];
        nb1[r] = -2.0f * bk[n + 32];
    }

    float base = a0[0];
    for (int k = 0; k < 64; ++k) base += bk[k];  // uniform -> scalar ops

    const int wid = (int)((blockIdx.x * blockDim.x + threadIdx.x) >> 6);
    const int nw  = (int)((gridDim.x * blockDim.x) >> 6);

    int tile = wid;
    floatx4 z0, z1;                       // pipeline registers (current tile)
    if (tile < ntiles) {
        const float* zp = z + (size_t)(tile * 32 + m) * 16 + g * 8;
        z0 = *(const floatx4*)zp;
        z1 = *(const floatx4*)(zp + 4);
    }

    while (tile < ntiles) {
        const int next = tile + nw;
        floatx4 p0, p1;                   // prefetch next tile (wave-uniform branch)
        if (next < ntiles) {
            const float* zp = z + (size_t)(next * 32 + m) * 16 + g * 8;
            p0 = *(const floatx4*)zp;
            p1 = *(const floatx4*)(zp + 4);
        }

        Frag bfr;
        bfr.s[0] = f2bf(z0.x); bfr.s[1] = f2bf(z0.y);
        bfr.s[2] = f2bf(z0.z); bfr.s[3] = f2bf(z0.w);
        bfr.s[4] = f2bf(z1.x); bfr.s[5] = f2bf(z1.y);
        bfr.s[6] = f2bf(z1.z); bfr.s[7] = f2bf(z1.w);

        floatx16 acc0 = __builtin_amdgcn_mfma_f32_32x32x16_bf16(af0.v, bfr.v, cinit0, 0, 0, 0);
        floatx16 acc1 = __builtin_amdgcn_mfma_f32_32x32x16_bf16(af1.v, bfr.v, cinit1, 0, 0, 0);

        float y0 = 0.0f, y1 = 0.0f;       // dual accumulators for FMA ILP
        #pragma unroll
        for (int r = 0; r < 16; ++r) {
            float e0 = fast_exp2(acc0[r]);
            float e1 = fast_exp2(acc1[r]);
            y0 += nb0[r] * fast_rcp(e0 + 1.0f);
            y1 += nb1[r] * fast_rcp(e1 + 1.0f);
        }
        float y = y0 + y1;
        y += __shfl_xor(y, 32, 64);       // merge complementary node half
        if (g == 0) out[tile * 32 + m] = base + y;

        z0 = p0; z1 = p1;
        tile = next;
    }
}

extern "C" void kernel_launch(void* const* d_in, const int* in_sizes, int n_in,
                              void* d_out, int out_size, void* d_ws, size_t ws_size,
                              hipStream_t stream) {
    const float* z  = (const float*)d_in[0];
    const float* a0 = (const float*)d_in[1];
    const float* bk = (const float*)d_in[2];
    const float* ck = (const float*)d_in[3];
    const float* dk = (const float*)d_in[4];
    float* out = (float*)d_out;

    const int B      = in_sizes[0] / 16;   // z is [B,16]
    const int ntiles = B / 32;             // 32 batch rows per wave-tile

    dim3 grid(2048), block(256);           // 8192 waves -> exactly 8 tiles/wave
    hipLaunchKernelGGL(mave_kernel, grid, block, 0, stream,
                       z, a0, bk, ck, dk, out, ntiles);
}

// Round 3
// 202.629 us; speedup vs baseline: 1.0230x; 1.0230x over previous
//
#include <hip/hip_runtime.h>
#include <stdint.h>

typedef __attribute__((ext_vector_type(8)))  short  short8;
typedef __attribute__((ext_vector_type(8)))  __bf16 bf16x8;
typedef __attribute__((ext_vector_type(16))) float  floatx16;
typedef __attribute__((ext_vector_type(4)))  float  floatx4;
typedef __attribute__((ext_vector_type(4)))  uint32_t uint4v;

union Frag  { short8 s; bf16x8 v; uint4v d; };
union FU    { float f; uint32_t u; };

// round-to-nearest-even f32 -> bf16 (used only in one-time setup)
__device__ __forceinline__ short f2bf(float f) {
    FU x; x.f = f;
    uint32_t r = x.u + 0x7fffu + ((x.u >> 16) & 1u);
    return (short)(r >> 16);
}

// pack two f32 -> bf16x2 dword with round-half-up: 2 adds + 1 v_perm
__device__ __forceinline__ uint32_t pack_bf2(float lo, float hi) {
    FU a, b; a.f = lo; b.f = hi;
    uint32_t ra = a.u + 0x8000u;
    uint32_t rb = b.u + 0x8000u;
    // bytes: dst = [rb.3, rb.2, ra.3, ra.2]  (hi16 of each)
    return __builtin_amdgcn_perm(rb, ra, 0x07060302u);
}

__device__ __forceinline__ float fast_exp2(float x) {
#if __has_builtin(__builtin_amdgcn_exp2f)
    return __builtin_amdgcn_exp2f(x);
#else
    return exp2f(x);
#endif
}

__device__ __forceinline__ float fast_rcp(float x) {
#if __has_builtin(__builtin_amdgcn_rcpf)
    return __builtin_amdgcn_rcpf(x);
#else
    return 1.0f / x;
#endif
}

// y[b] = a0 + sum_k bk[k] * tanh(ck[k,:].z[b,:] + dk[k])
//
// D = mfma_32x32x16_bf16(A=s*ck, B=z, C=s*dk) -> D[node][row] = s*(dot+dk),
// s = 2*log2(e); col(lane&31)=batch row, row(reg-map)=node.
// tanh(t) = 1 - 2/(exp2(s*t)+1) -> contribution = bk - 2*bk*rcp(E+1).
// E->inf => rcp->0 => tanh->1 (correct saturation, no clamp needed).
//
// R3: VGPR diet for 4 waves/SIMD (was ~3): nb coeffs packed bf16x2
// (-16 VGPRs), z->bf16 via add+v_perm (24 ops/tile vs ~56).
__global__ __launch_bounds__(256) void mave_kernel(
    const float* __restrict__ z,
    const float* __restrict__ a0,
    const float* __restrict__ bk,
    const float* __restrict__ ck,
    const float* __restrict__ dk,
    float* __restrict__ out,
    int ntiles)
{
    const int lane = threadIdx.x & 63;
    const int m    = lane & 31;   // node for A-frag; batch-row-in-tile for B-frag
    const int g    = lane >> 5;
    const float S  = 2.885390081777927f;  // 2*log2(e)

    // A-operand fragments: rows of s*ck (node = m and m+32), k = g*8+e
    Frag af0, af1;
    {
        const float* c0 = ck + m * 16 + g * 8;
        const float* c1 = c0 + 32 * 16;
        #pragma unroll
        for (int e = 0; e < 8; ++e) {
            af0.s[e] = f2bf(c0[e] * S);
            af1.s[e] = f2bf(c1[e] * S);
        }
    }

    // C-operand init = s*dk[node]; node map (reg&3)+8*(reg>>2)+4*g.
    // nb = -2*bk[node], packed bf16x2: lo = nodes 0-31 half, hi = +32 half.
    floatx16 cinit0, cinit1;
    uint32_t nbp[16];
    #pragma unroll
    for (int r = 0; r < 16; ++r) {
        int n = (r & 3) + 8 * (r >> 2) + 4 * g;
        cinit0[r] = S * dk[n];
        cinit1[r] = S * dk[n + 32];
        nbp[r] = pack_bf2(-2.0f * bk[n], -2.0f * bk[n + 32]);
    }

    float base = a0[0];
    for (int k = 0; k < 64; ++k) base += bk[k];  // uniform -> scalar ops

    const int wid = (int)((blockIdx.x * blockDim.x + threadIdx.x) >> 6);
    const int nw  = (int)((gridDim.x * blockDim.x) >> 6);

    int tile = wid;
    floatx4 z0, z1;                       // pipeline registers (current tile)
    if (tile < ntiles) {
        const float* zp = z + (size_t)(tile * 32 + m) * 16 + g * 8;
        z0 = *(const floatx4*)zp;
        z1 = *(const floatx4*)(zp + 4);
    }

    while (tile < ntiles) {
        const int next = tile + nw;
        floatx4 p0, p1;                   // prefetch next tile (wave-uniform branch)
        if (next < ntiles) {
            const float* zp = z + (size_t)(next * 32 + m) * 16 + g * 8;
            p0 = *(const floatx4*)zp;
            p1 = *(const floatx4*)(zp + 4);
        }

        // z -> bf16 B-frag: 8 adds + 4 perms per half
        Frag bfr;
        bfr.d[0] = pack_bf2(z0.x, z0.y);
        bfr.d[1] = pack_bf2(z0.z, z0.w);
        bfr.d[2] = pack_bf2(z1.x, z1.y);
        bfr.d[3] = pack_bf2(z1.z, z1.w);

        floatx16 acc0 = __builtin_amdgcn_mfma_f32_32x32x16_bf16(af0.v, bfr.v, cinit0, 0, 0, 0);
        floatx16 acc1 = __builtin_amdgcn_mfma_f32_32x32x16_bf16(af1.v, bfr.v, cinit1, 0, 0, 0);

        float y0 = 0.0f, y1 = 0.0f;       // dual accumulators for FMA ILP
        #pragma unroll
        for (int r = 0; r < 16; ++r) {
            float e0 = fast_exp2(acc0[r]);
            float e1 = fast_exp2(acc1[r]);
            float r0 = fast_rcp(e0 + 1.0f);
            float r1 = fast_rcp(e1 + 1.0f);
            FU lo, hi;
            lo.u = nbp[r] << 16;          // bf16 -> f32 unpack, 1 op each
            hi.u = nbp[r] & 0xffff0000u;
            y0 += lo.f * r0;
            y1 += hi.f * r1;
        }
        float y = y0 + y1;
        y += __shfl_xor(y, 32, 64);       // merge complementary node half
        if (g == 0) out[tile * 32 + m] = base + y;

        z0 = p0; z1 = p1;
        tile = next;
    }
}

extern "C" void kernel_launch(void* const* d_in, const int* in_sizes, int n_in,
                              void* d_out, int out_size, void* d_ws, size_t ws_size,
                              hipStream_t stream) {
    const float* z  = (const float*)d_in[0];
    const float* a0 = (const float*)d_in[1];
    const float* bk = (const float*)d_in[2];
    const float* ck = (const float*)d_in[3];
    const float* dk = (const float*)d_in[4];
    float* out = (float*)d_out;

    const int B      = in_sizes[0] / 16;   // z is [B,16]
    const int ntiles = B / 32;             // 32 batch rows per wave-tile

    dim3 grid(2048), block(256);           // 8192 waves -> 8 tiles/wave
    hipLaunchKernelGGL(mave_kernel, grid, block, 0, stream,
                       z, a0, bk, ck, dk, out, ntiles);
}